// Round 6
// baseline (36.188 us; speedup 1.0000x reference)
//
#include <hip/hip_runtime.h>
#include <math.h>

#define D 128
// level 0: R=24 rows/graph (nodes); level 1: R=40 (line graph)
// out (floats): s_h@0, s_t@32768, s_h_line@65536, s_t_line@98304
// ws: fp16 M0@0 [128x128], M1@16384; then f32 aux @byte 65536:
//     aux[0..127]=w0_level0, aux[128..255]=w0_level1, aux[256..257]=c0

typedef float f32x4 __attribute__((ext_vector_type(4)));
typedef _Float16 f16x8 __attribute__((ext_vector_type(8)));

union PK4 { _Float16 h[4]; ushort4 v; };

__device__ __forceinline__ f16x8 cvt8(float4 a, float4 b) {
    f16x8 r;
    r[0] = (_Float16)a.x; r[1] = (_Float16)a.y; r[2] = (_Float16)a.z; r[3] = (_Float16)a.w;
    r[4] = (_Float16)b.x; r[5] = (_Float16)b.y; r[6] = (_Float16)b.z; r[7] = (_Float16)b.w;
    return r;
}

__device__ __forceinline__ float dot8(float4 a, float4 b, float4 wa, float4 wb) {
    return a.x*wa.x + a.y*wa.y + a.z*wa.z + a.w*wa.w
         + b.x*wb.x + b.y*wb.y + b.z*wb.z + b.w*wb.w;
}

__device__ __forceinline__ float tanh_fast(float x) {
    float cx = fminf(fmaxf(x, -15.f), 15.f);
    float t = __expf(2.f * cx);
    return __fdividef(t - 1.f, t + 1.f);
}

// ---- prep: M = Wh^T Wt + Wt^T Wh (fp16), w0 = Wh^T bt + Wt^T bh, c0 = 2 bh.bt ----
// 64 blocks x 256 thr; block bid: level = bid>>5, a = (bid&31)*4 + (tid>>7)*2 + rep.
__global__ __launch_bounds__(256) void prep_M(
    const float* __restrict__ Wh, const float* __restrict__ Wt,
    const float* __restrict__ Whl, const float* __restrict__ Wtl,
    const float* __restrict__ bh, const float* __restrict__ bt,
    const float* __restrict__ bhl, const float* __restrict__ btl,
    _Float16* __restrict__ M16, float* __restrict__ aux)
{
    const int bid = blockIdx.x, tid = threadIdx.x;
    const int level = bid >> 5;
    const float* __restrict__ WH = level ? Whl : Wh;
    const float* __restrict__ WT = level ? Wtl : Wt;
    const int b = tid & 127;
    const int asub = tid >> 7;
    _Float16* M = M16 + level * 16384;

#pragma unroll
    for (int rep = 0; rep < 2; ++rep) {
        const int a = (bid & 31) * 4 + asub * 2 + rep;
        float s = 0.f;
#pragma unroll 4
        for (int k = 0; k < 128; ++k) {
            float wha = WH[k * 128 + a], wta = WT[k * 128 + a];
            float whb = WH[k * 128 + b], wtb = WT[k * 128 + b];
            s += wha * wtb + wta * whb;
        }
        M[a * 128 + b] = (_Float16)s;
    }
    if ((bid & 31) == 0) {
        const float* BH = level ? bhl : bh;
        const float* BT = level ? btl : bt;
        if (tid < 128) {
            float s = 0.f;
#pragma unroll 4
            for (int k = 0; k < 128; ++k)
                s += WH[k * 128 + tid] * BT[k] + WT[k * 128 + tid] * BH[k];
            aux[level * 128 + tid] = s;
        } else if (tid == 128) {
            float c = 0.f;
            for (int k = 0; k < 128; ++k) c += BH[k] * BT[k];
            aux[256 + level] = 2.f * c;
        }
    }
}

// ---- fused per-(level,graph) kernel ----
// MFMA rule (validated r1-r5): mfma(P,Q): lane(lm,lq) reg r = dot(P_row[lq*4+r], Q_row[lm]);
// fragments loaded with row = lane&15, k = (lane>>4)*8 + e.
template <int LEVEL>
__device__ __forceinline__ void body(
    int g, const float* __restrict__ xh, const float* __restrict__ xt,
    const _Float16* __restrict__ M16, const float* __restrict__ aux,
    float* __restrict__ osh, float* __restrict__ ost,
    _Float16* Ylds, float* u_s, float* v_s,
    float* colpart, float* bh_s, float* pt_s, float* ph_s)
{
    constexpr int R = LEVEL ? 40 : 24;
    constexpr int TM = LEVEL ? 3 : 2;
    constexpr float invR = 1.f / (float)R;

    const int tid = threadIdx.x;
    const int w = tid >> 6, l = tid & 63;
    const int lm = l & 15, lq = l >> 4;
    const int base = g * R;

    const _Float16* __restrict__ M = M16 + LEVEL * 16384;
    const float* __restrict__ w0 = aux + LEVEL * 128;
    const float c0 = aux[256 + LEVEL];

    // --- prefetch xt alpha fragments (B operand) early; wave1 also v partials ---
    f16x8 bq[TM][4];
    float pv[TM];
#pragma unroll
    for (int tj = 0; tj < TM; ++tj) pv[tj] = 0.f;
    if (w < TM) {
#pragma unroll
        for (int ksa = 0; ksa < 4; ++ksa) {
            const int k0 = ksa * 32 + lq * 8;
            float4 wa, wb;
            if (w == 1) {
                wa = *reinterpret_cast<const float4*>(w0 + k0);
                wb = *reinterpret_cast<const float4*>(w0 + k0 + 4);
            }
#pragma unroll
            for (int tj = 0; tj < TM; ++tj) {
                int j = tj * 16 + lm;
                int jc = (j < R) ? j : (R - 1);
                const float* xr = xt + (base + jc) * D + k0;
                float4 va = *reinterpret_cast<const float4*>(xr);
                float4 vb = *reinterpret_cast<const float4*>(xr + 4);
                bq[tj][ksa] = cvt8(va, vb);
                if (w == 1) pv[tj] += dot8(va, vb, wa, wb);
            }
        }
    }

    // --- Y = xh @ M (R x 128); wave w owns col tiles {w*2, w*2+1}; wave0 u partials ---
    f32x4 accY[TM][2];
#pragma unroll
    for (int ti = 0; ti < TM; ++ti)
#pragma unroll
        for (int c2 = 0; c2 < 2; ++c2) accY[ti][c2] = (f32x4){0.f, 0.f, 0.f, 0.f};
    float pu[TM];
#pragma unroll
    for (int ti = 0; ti < TM; ++ti) pu[ti] = 0.f;

#pragma unroll
    for (int ks = 0; ks < 4; ++ks) {
        const int k0 = ks * 32 + lq * 8;
        float4 wa, wb;
        if (w == 0) {
            wa = *reinterpret_cast<const float4*>(w0 + k0);
            wb = *reinterpret_cast<const float4*>(w0 + k0 + 4);
        }
        f16x8 q[TM];
#pragma unroll
        for (int ti = 0; ti < TM; ++ti) {
            int i = ti * 16 + lm;
            int ic = (i < R) ? i : (R - 1);
            const float* xr = xh + (base + ic) * D + k0;
            float4 va = *reinterpret_cast<const float4*>(xr);
            float4 vb = *reinterpret_cast<const float4*>(xr + 4);
            q[ti] = cvt8(va, vb);
            if (w == 0) pu[ti] += dot8(va, vb, wa, wb);
        }
#pragma unroll
        for (int c2 = 0; c2 < 2; ++c2) {
            const int ctl = w * 2 + c2;
            f16x8 P = *reinterpret_cast<const f16x8*>(M + (ctl * 16 + lm) * 128 + k0);
#pragma unroll
            for (int ti = 0; ti < TM; ++ti)
                accY[ti][c2] = __builtin_amdgcn_mfma_f32_16x16x32_f16(P, q[ti], accY[ti][c2], 0, 0, 0);
        }
    }

    // u / v reduce over lq, store valid entries
    if (w == 0) {
#pragma unroll
        for (int ti = 0; ti < TM; ++ti) {
            float s = pu[ti];
            s += __shfl_xor(s, 16, 64);
            s += __shfl_xor(s, 32, 64);
            int i = ti * 16 + lm;
            if (lq == 0 && i < R) u_s[i] = s;
        }
    } else if (w == 1) {
#pragma unroll
        for (int tj = 0; tj < TM; ++tj) {
            float s = pv[tj];
            s += __shfl_xor(s, 16, 64);
            s += __shfl_xor(s, 32, 64);
            int j = tj * 16 + lm;
            if (lq == 0 && j < R) v_s[j] = s;
        }
    }

    // Y epilogue -> LDS fp16, XOR swizzle (half-col ^= (row&7)<<3)
#pragma unroll
    for (int c2 = 0; c2 < 2; ++c2) {
        const int nc = (w * 2 + c2) * 16 + lq * 4;
#pragma unroll
        for (int ti = 0; ti < TM; ++ti) {
            int i = ti * 16 + lm;
            if (i < R) {
                PK4 pk;
                pk.h[0] = (_Float16)accY[ti][c2][0];
                pk.h[1] = (_Float16)accY[ti][c2][1];
                pk.h[2] = (_Float16)accY[ti][c2][2];
                pk.h[3] = (_Float16)accY[ti][c2][3];
                *reinterpret_cast<ushort4*>(&Ylds[i * 128 + (nc ^ ((i & 7) << 3))]) = pk.v;
            }
        }
    }
    __syncthreads();

    // --- alpha tile: S = Y @ xt^T + u_i + v_j + c0; wave w owns i-tile w ---
    float cs[3] = {0.f, 0.f, 0.f};
    if (w < TM) {
        f32x4 acc2[TM];
#pragma unroll
        for (int tj = 0; tj < TM; ++tj) acc2[tj] = (f32x4){0.f, 0.f, 0.f, 0.f};

        const int ri = w * 16 + lm;
        const int ric = (ri < R) ? ri : (R - 1);
#pragma unroll
        for (int ksa = 0; ksa < 4; ++ksa) {
            const int k0 = ksa * 32 + lq * 8;
            f16x8 A = *reinterpret_cast<const f16x8*>(&Ylds[ric * 128 + (k0 ^ ((ric & 7) << 3))]);
#pragma unroll
            for (int tj = 0; tj < TM; ++tj)
                acc2[tj] = __builtin_amdgcn_mfma_f32_16x16x32_f16(A, bq[tj][ksa], acc2[tj], 0, 0, 0);
        }

        float at[TM][4];
#pragma unroll
        for (int tj = 0; tj < TM; ++tj) {
            int j = tj * 16 + lm;
            bool vj = (j < R);
            float vjv = v_s[vj ? j : 0];
#pragma unroll
            for (int r = 0; r < 4; ++r) {
                int i = w * 16 + lq * 4 + r;
                bool vi = (i < R);
                float uiv = u_s[vi ? i : 0];
                float sv = acc2[tj][r] + uiv + vjv + c0;
                at[tj][r] = (vi && vj) ? tanh_fast(sv) : 0.f;
            }
        }

        // row sums over j -> bh_s[i]
#pragma unroll
        for (int r = 0; r < 4; ++r) {
            float s = 0.f;
#pragma unroll
            for (int tj = 0; tj < TM; ++tj) s += at[tj][r];
            s += __shfl_xor(s, 1, 64);
            s += __shfl_xor(s, 2, 64);
            s += __shfl_xor(s, 4, 64);
            s += __shfl_xor(s, 8, 64);
            if (lm == 0) bh_s[w * 16 + lq * 4 + r] = s;
        }
        // col partial sums over this i-tile
#pragma unroll
        for (int tj = 0; tj < TM; ++tj) {
            float s = 0.f;
#pragma unroll
            for (int r = 0; r < 4; ++r) s += at[tj][r];
            s += __shfl_xor(s, 16, 64);
            s += __shfl_xor(s, 32, 64);
            cs[tj] = s;
        }
    }
#pragma unroll
    for (int tj = 0; tj < 3; ++tj)
        if (lq == 0) colpart[w * 48 + tj * 16 + lm] = (tj < TM) ? cs[tj] : 0.f;
    __syncthreads();

    // softmaxes: wave0 -> p_t (col means), wave1 -> p_h (row means)
    if (w == 0) {
        float v = (l < 48) ? (colpart[l] + colpart[48 + l] + colpart[96 + l] + colpart[144 + l]) : 0.f;
        float val = (l < R) ? v * invR : -INFINITY;
        float m = val;
        for (int o = 32; o; o >>= 1) m = fmaxf(m, __shfl_xor(m, o, 64));
        float e = (l < R) ? __expf(val - m) : 0.f;
        float s = e;
        for (int o = 32; o; o >>= 1) s += __shfl_xor(s, o, 64);
        if (l < R) pt_s[l] = e / s;
    } else if (w == 1) {
        float val = (l < R) ? bh_s[l] * invR : -INFINITY;
        float m = val;
        for (int o = 32; o; o >>= 1) m = fmaxf(m, __shfl_xor(m, o, 64));
        float e = (l < R) ? __expf(val - m) : 0.f;
        float s = e;
        for (int o = 32; o; o >>= 1) s += __shfl_xor(s, o, 64);
        if (l < R) ph_s[l] = e / s;
    }
    __syncthreads();

    // outputs: threads 0..127 -> s_t col c; 128..255 -> s_h col c
    if (tid < 128) {
        int c = tid;
        float a = 0.f;
        for (int j = 0; j < R; ++j) a += pt_s[j] * xt[(base + j) * D + c];
        ost[g * D + c] = a;
    } else {
        int c = tid - 128;
        float a = 0.f;
        for (int i = 0; i < R; ++i) a += ph_s[i] * xh[(base + i) * D + c];
        osh[g * D + c] = a;
    }
}

__global__ __launch_bounds__(256, 2) void fused_kernel(
    const float* __restrict__ xnh, const float* __restrict__ xnt,
    const float* __restrict__ xlh, const float* __restrict__ xlt,
    const _Float16* __restrict__ M16, const float* __restrict__ aux,
    float* __restrict__ out)
{
    __shared__ __align__(16) _Float16 Ylds[48 * 128];
    __shared__ float u_s[48], v_s[48], colpart[192], bh_s[48], pt_s[48], ph_s[48];

    int idx = blockIdx.x;
    if (idx < 256)
        body<0>(idx, xnh, xnt, M16, aux, out + 0, out + 32768,
                Ylds, u_s, v_s, colpart, bh_s, pt_s, ph_s);
    else
        body<1>(idx - 256, xlh, xlt, M16, aux, out + 65536, out + 98304,
                Ylds, u_s, v_s, colpart, bh_s, pt_s, ph_s);
}

extern "C" void kernel_launch(void* const* d_in, const int* in_sizes, int n_in,
                              void* d_out, int out_size, void* d_ws, size_t ws_size,
                              hipStream_t stream) {
    const float* xnh   = (const float*)d_in[0];
    const float* xnt   = (const float*)d_in[1];
    const float* xlh   = (const float*)d_in[2];
    const float* xlt   = (const float*)d_in[3];
    const float* Wh_w  = (const float*)d_in[4];
    const float* Wh_b  = (const float*)d_in[5];
    const float* Wt_w  = (const float*)d_in[6];
    const float* Wt_b  = (const float*)d_in[7];
    const float* Whl_w = (const float*)d_in[8];
    const float* Whl_b = (const float*)d_in[9];
    const float* Wtl_w = (const float*)d_in[10];
    const float* Wtl_b = (const float*)d_in[11];

    _Float16* M16 = (_Float16*)d_ws;
    float* aux = (float*)((char*)d_ws + 65536);
    float* out = (float*)d_out;

    prep_M<<<64, 256, 0, stream>>>(Wh_w, Wt_w, Whl_w, Wtl_w,
                                   Wh_b, Wt_b, Whl_b, Wtl_b, M16, aux);
    fused_kernel<<<512, 256, 0, stream>>>(xnh, xnt, xlh, xlt, M16, aux, out);
}

// Round 7
// 24.901 us; speedup vs baseline: 1.4533x; 1.4533x over previous
//
#include <hip/hip_runtime.h>
#include <math.h>

#define D 128
// level 0: R=24 rows/graph (nodes); level 1: R=40 (line graph)
// out (floats): s_h@0, s_t@32768, s_h_line@65536, s_t_line@98304

typedef float f32x4 __attribute__((ext_vector_type(4)));
typedef _Float16 f16x8 __attribute__((ext_vector_type(8)));

union PK4 { _Float16 h[4]; ushort4 v; };

__device__ __forceinline__ f16x8 cvt8(float4 a, float4 b) {
    f16x8 r;
    r[0] = (_Float16)a.x; r[1] = (_Float16)a.y; r[2] = (_Float16)a.z; r[3] = (_Float16)a.w;
    r[4] = (_Float16)b.x; r[5] = (_Float16)b.y; r[6] = (_Float16)b.z; r[7] = (_Float16)b.w;
    return r;
}

__device__ __forceinline__ float tanh_fast(float x) {
    float cx = fminf(fmaxf(x, -15.f), 15.f);
    float t = __expf(2.f * cx);
    return __fdividef(t - 1.f, t + 1.f);
}

// MFMA rule (validated r1-r6): mfma(P,Q): lane(lm,lq) reg r = dot(P_row[lq*4+r], Q_row[lm]);
// fragments loaded with row = lane&15, k = (lane>>4)*8 + e.
template <int LEVEL>
__device__ __forceinline__ void body(
    int g, const float* __restrict__ xh, const float* __restrict__ xt,
    const float* __restrict__ WH, const float* __restrict__ WT,
    const float* __restrict__ bH, const float* __restrict__ bT,
    float* __restrict__ osh, float* __restrict__ ost,
    _Float16* GH, _Float16* GT,
    float* colpart, float* bh_s, float* pt_s, float* ph_s)
{
    constexpr int R = LEVEL ? 40 : 24;
    constexpr int TM = LEVEL ? 3 : 2;
    constexpr float invR = 1.f / (float)R;

    const int tid = threadIdx.x;
    const int w = tid >> 6, l = tid & 63;
    const int lm = l & 15, lq = l >> 4;
    const int base = g * R;
    const int tile0 = 2 * w;          // this wave owns W row-tiles {tile0, tile0+1} of Wh AND Wt

    // ---- load all W fragments once (reused by both G_h and G_t) ----
    f16x8 wf[4][4];                   // [0,1]=WH tiles, [2,3]=WT tiles; x [ks]
#pragma unroll
    for (int ks = 0; ks < 4; ++ks) {
        const int k0 = ks * 32 + lq * 8;
#pragma unroll
        for (int t = 0; t < 2; ++t) {
            const float* p1 = WH + ((tile0 + t) * 16 + lm) * D + k0;
            wf[t][ks] = cvt8(*reinterpret_cast<const float4*>(p1),
                             *reinterpret_cast<const float4*>(p1 + 4));
            const float* p2 = WT + ((tile0 + t) * 16 + lm) * D + k0;
            wf[2 + t][ks] = cvt8(*reinterpret_cast<const float4*>(p2),
                                 *reinterpret_cast<const float4*>(p2 + 4));
        }
    }

    // ---- G_s = x_s @ [WA|WB]^T + [bA|bB], wave owns 4 col-tiles; store fp16 LDS ----
#pragma unroll
    for (int side = 0; side < 2; ++side) {
        const float* __restrict__ X  = side ? xt : xh;
        const float* __restrict__ bA = side ? bT : bH;
        const float* __restrict__ bB = side ? bH : bT;
        _Float16* Gs = side ? GT : GH;

        f32x4 acc[TM][4];
#pragma unroll
        for (int ti = 0; ti < TM; ++ti)
#pragma unroll
            for (int c2 = 0; c2 < 4; ++c2) acc[ti][c2] = (f32x4){0.f, 0.f, 0.f, 0.f};

#pragma unroll
        for (int ks = 0; ks < 4; ++ks) {
            const int k0 = ks * 32 + lq * 8;
            f16x8 q[TM];
#pragma unroll
            for (int ti = 0; ti < TM; ++ti) {
                int i = ti * 16 + lm;
                int ic = (i < R) ? i : (R - 1);
                const float* xr = X + (base + ic) * D + k0;
                q[ti] = cvt8(*reinterpret_cast<const float4*>(xr),
                             *reinterpret_cast<const float4*>(xr + 4));
            }
#pragma unroll
            for (int c2 = 0; c2 < 4; ++c2) {
                const int wfidx = side ? (c2 ^ 2) : c2;   // side t: WT tiles first
#pragma unroll
                for (int ti = 0; ti < TM; ++ti)
                    acc[ti][c2] = __builtin_amdgcn_mfma_f32_16x16x32_f16(
                        wf[wfidx][ks], q[ti], acc[ti][c2], 0, 0, 0);
            }
        }

        // epilogue: lane holds G[i=ti*16+lm][n=ctl*16+lq*4+r]
#pragma unroll
        for (int c2 = 0; c2 < 4; ++c2) {
            const int ctl = (c2 < 2) ? (tile0 + c2) : (8 + tile0 + (c2 - 2));
            const int nc = ctl * 16 + lq * 4;
            const float* bp = (ctl < 8) ? (bA + nc) : (bB + nc - 128);
            float4 b4 = *reinterpret_cast<const float4*>(bp);
#pragma unroll
            for (int ti = 0; ti < TM; ++ti) {
                int i = ti * 16 + lm;
                if (i < R) {
                    PK4 pk;
                    pk.h[0] = (_Float16)(acc[ti][c2][0] + b4.x);
                    pk.h[1] = (_Float16)(acc[ti][c2][1] + b4.y);
                    pk.h[2] = (_Float16)(acc[ti][c2][2] + b4.z);
                    pk.h[3] = (_Float16)(acc[ti][c2][3] + b4.w);
                    *reinterpret_cast<ushort4*>(&Gs[i * 256 + (nc ^ ((i & 7) << 3))]) = pk.v;
                }
            }
        }
    }
    __syncthreads();

    // ---- alpha = tanh(G_h @ G_t^T); wave w<TM owns i-tile w ----
    float cs[3] = {0.f, 0.f, 0.f};
    if (w < TM) {
        const f16x8 z8 = {0, 0, 0, 0, 0, 0, 0, 0};
        f32x4 acc2[TM];
#pragma unroll
        for (int tj = 0; tj < TM; ++tj) acc2[tj] = (f32x4){0.f, 0.f, 0.f, 0.f};

        const int ri = w * 16 + lm;
        const bool vi = (ri < R);
        const int ric = vi ? ri : (R - 1);
        int rjc[TM];
        bool vj[TM];
#pragma unroll
        for (int tj = 0; tj < TM; ++tj) {
            int rj = tj * 16 + lm;
            vj[tj] = (rj < R);
            rjc[tj] = vj[tj] ? rj : (R - 1);
        }
#pragma unroll
        for (int ksa = 0; ksa < 8; ++ksa) {
            const int k0 = ksa * 32 + lq * 8;
            f16x8 A = *reinterpret_cast<const f16x8*>(&GH[ric * 256 + (k0 ^ ((ric & 7) << 3))]);
            A = vi ? A : z8;
#pragma unroll
            for (int tj = 0; tj < TM; ++tj) {
                f16x8 B = *reinterpret_cast<const f16x8*>(&GT[rjc[tj] * 256 + (k0 ^ ((rjc[tj] & 7) << 3))]);
                B = vj[tj] ? B : z8;
                acc2[tj] = __builtin_amdgcn_mfma_f32_16x16x32_f16(A, B, acc2[tj], 0, 0, 0);
            }
        }

        float at[TM][4];
#pragma unroll
        for (int tj = 0; tj < TM; ++tj)
#pragma unroll
            for (int r = 0; r < 4; ++r) at[tj][r] = tanh_fast(acc2[tj][r]);

        // row sums over j -> bh_s[i]; padded entries are tanh(0)=0
#pragma unroll
        for (int r = 0; r < 4; ++r) {
            float s = 0.f;
#pragma unroll
            for (int tj = 0; tj < TM; ++tj) s += at[tj][r];
            s += __shfl_xor(s, 1, 64);
            s += __shfl_xor(s, 2, 64);
            s += __shfl_xor(s, 4, 64);
            s += __shfl_xor(s, 8, 64);
            if (lm == 0) bh_s[w * 16 + lq * 4 + r] = s;
        }
        // col partial sums over this i-tile
#pragma unroll
        for (int tj = 0; tj < TM; ++tj) {
            float s = 0.f;
#pragma unroll
            for (int r = 0; r < 4; ++r) s += at[tj][r];
            s += __shfl_xor(s, 16, 64);
            s += __shfl_xor(s, 32, 64);
            cs[tj] = s;
        }
    }
#pragma unroll
    for (int tj = 0; tj < 3; ++tj)
        if (lq == 0) colpart[w * 48 + tj * 16 + lm] = (tj < TM) ? cs[tj] : 0.f;
    __syncthreads();

    // softmaxes: wave0 -> p_t (col means), wave1 -> p_h (row means)
    if (w == 0) {
        float v = (l < 48) ? (colpart[l] + colpart[48 + l] + colpart[96 + l] + colpart[144 + l]) : 0.f;
        float val = (l < R) ? v * invR : -INFINITY;
        float m = val;
        for (int o = 32; o; o >>= 1) m = fmaxf(m, __shfl_xor(m, o, 64));
        float e = (l < R) ? __expf(val - m) : 0.f;
        float s = e;
        for (int o = 32; o; o >>= 1) s += __shfl_xor(s, o, 64);
        if (l < R) pt_s[l] = e / s;
    } else if (w == 1) {
        float val = (l < R) ? bh_s[l] * invR : -INFINITY;
        float m = val;
        for (int o = 32; o; o >>= 1) m = fmaxf(m, __shfl_xor(m, o, 64));
        float e = (l < R) ? __expf(val - m) : 0.f;
        float s = e;
        for (int o = 32; o; o >>= 1) s += __shfl_xor(s, o, 64);
        if (l < R) ph_s[l] = e / s;
    }
    __syncthreads();

    // outputs: threads 0..127 -> s_t col c; 128..255 -> s_h col c (x rows are L2-hot)
    if (tid < 128) {
        int c = tid;
        float a = 0.f;
        for (int j = 0; j < R; ++j) a += pt_s[j] * xt[(base + j) * D + c];
        ost[g * D + c] = a;
    } else {
        int c = tid - 128;
        float a = 0.f;
        for (int i = 0; i < R; ++i) a += ph_s[i] * xh[(base + i) * D + c];
        osh[g * D + c] = a;
    }
}

__global__ __launch_bounds__(256, 2) void fused_kernel(
    const float* __restrict__ xnh, const float* __restrict__ xnt,
    const float* __restrict__ xlh, const float* __restrict__ xlt,
    const float* __restrict__ Wh, const float* __restrict__ bh,
    const float* __restrict__ Wt, const float* __restrict__ bt,
    const float* __restrict__ Whl, const float* __restrict__ bhl,
    const float* __restrict__ Wtl, const float* __restrict__ btl,
    float* __restrict__ out)
{
    __shared__ __align__(16) _Float16 GH[48 * 256];
    __shared__ __align__(16) _Float16 GT[48 * 256];
    __shared__ float colpart[192], bh_s[48], pt_s[48], ph_s[48];

    int idx = blockIdx.x;
    if (idx < 256)
        body<0>(idx, xnh, xnt, Wh, Wt, bh, bt, out + 0, out + 32768,
                GH, GT, colpart, bh_s, pt_s, ph_s);
    else
        body<1>(idx - 256, xlh, xlt, Whl, Wtl, bhl, btl, out + 65536, out + 98304,
                GH, GT, colpart, bh_s, pt_s, ph_s);
}

extern "C" void kernel_launch(void* const* d_in, const int* in_sizes, int n_in,
                              void* d_out, int out_size, void* d_ws, size_t ws_size,
                              hipStream_t stream) {
    const float* xnh   = (const float*)d_in[0];
    const float* xnt   = (const float*)d_in[1];
    const float* xlh   = (const float*)d_in[2];
    const float* xlt   = (const float*)d_in[3];
    const float* Wh_w  = (const float*)d_in[4];
    const float* Wh_b  = (const float*)d_in[5];
    const float* Wt_w  = (const float*)d_in[6];
    const float* Wt_b  = (const float*)d_in[7];
    const float* Whl_w = (const float*)d_in[8];
    const float* Whl_b = (const float*)d_in[9];
    const float* Wtl_w = (const float*)d_in[10];
    const float* Wtl_b = (const float*)d_in[11];

    float* out = (float*)d_out;

    fused_kernel<<<512, 256, 0, stream>>>(xnh, xnt, xlh, xlt,
                                          Wh_w, Wh_b, Wt_w, Wt_b,
                                          Whl_w, Whl_b, Wtl_w, Wtl_b, out);
}

// Round 8
// 21.764 us; speedup vs baseline: 1.6627x; 1.1441x over previous
//
#include <hip/hip_runtime.h>
#include <math.h>

#define D 128
// level 0: R=24 rows/graph (nodes); level 1: R=40 (line graph)
// out (floats): s_h@0, s_t@32768, s_h_line@65536, s_t_line@98304

typedef float f32x4 __attribute__((ext_vector_type(4)));
typedef _Float16 f16x8 __attribute__((ext_vector_type(8)));

union PK4 { _Float16 h[4]; ushort4 v; };

__device__ __forceinline__ f16x8 cvt8(float4 a, float4 b) {
    f16x8 r;
    r[0] = (_Float16)a.x; r[1] = (_Float16)a.y; r[2] = (_Float16)a.z; r[3] = (_Float16)a.w;
    r[4] = (_Float16)b.x; r[5] = (_Float16)b.y; r[6] = (_Float16)b.z; r[7] = (_Float16)b.w;
    return r;
}

__device__ __forceinline__ float tanh_fast(float x) {
    float cx = fminf(fmaxf(x, -15.f), 15.f);
    float t = __expf(2.f * cx);
    return __fdividef(t - 1.f, t + 1.f);
}

// MFMA rule (validated r1-r7): mfma(P,Q): lane(lm,lq) reg r = dot(P_row[lq*4+r], Q_row[lm]);
// fragments loaded with row = lane&15, k = (lane>>4)*8 + e.
// LDS swizzle (validated r4-r7): half-index k stored at k ^ ((row&7)<<3).
template <int LEVEL>
__device__ __forceinline__ void body(
    int g, const float* __restrict__ xh, const float* __restrict__ xt,
    const float* __restrict__ WH, const float* __restrict__ WT,
    const float* __restrict__ bH, const float* __restrict__ bT,
    float* __restrict__ osh, float* __restrict__ ost,
    _Float16* GH, _Float16* GT, _Float16* XH, _Float16* XT,
    float* colpart, float* bh_s, float* pt_s, float* ph_s)
{
    constexpr int R = LEVEL ? 40 : 24;
    constexpr int TM = LEVEL ? 3 : 2;
    constexpr int PAD = TM * 16;
    constexpr float invR = 1.f / (float)R;

    const int tid = threadIdx.x;
    const int w = tid >> 6, l = tid & 63;
    const int lm = l & 15, lq = l >> 4;
    const int base = g * R;
    const int tile0 = 2 * w;      // wave owns W row-tiles {tile0,tile0+1} of WH and WT

    // ---- W fragments once per wave, register-resident (issued first) ----
    f16x8 wf[4][4];               // [0,1]=WH tiles, [2,3]=WT tiles; x [ks]
#pragma unroll
    for (int ks = 0; ks < 4; ++ks) {
        const int k0 = ks * 32 + lq * 8;
#pragma unroll
        for (int t = 0; t < 2; ++t) {
            const float* p1 = WH + ((tile0 + t) * 16 + lm) * D + k0;
            wf[t][ks] = cvt8(*reinterpret_cast<const float4*>(p1),
                             *reinterpret_cast<const float4*>(p1 + 4));
            const float* p2 = WT + ((tile0 + t) * 16 + lm) * D + k0;
            wf[2 + t][ks] = cvt8(*reinterpret_cast<const float4*>(p2),
                                 *reinterpret_cast<const float4*>(p2 + 4));
        }
    }

    // ---- stage X -> LDS fp16 (swizzled, zero-padded rows R..PAD-1) ----
    {
        constexpr int UNITS = 2 * PAD * 32;          // float4 units
        for (int u = tid; u < UNITS; u += 256) {
            const int arr = (u >= PAD * 32);
            const int rem = arr ? (u - PAD * 32) : u;
            const int r = rem >> 5, c4 = rem & 31;
            _Float16* Xs = arr ? XT : XH;
            PK4 pk;
            if (r < R) {
                const float* xs = arr ? xt : xh;
                float4 v = *reinterpret_cast<const float4*>(&xs[(base + r) * D + c4 * 4]);
                pk.h[0] = (_Float16)v.x; pk.h[1] = (_Float16)v.y;
                pk.h[2] = (_Float16)v.z; pk.h[3] = (_Float16)v.w;
            } else {
                pk.v = make_ushort4(0, 0, 0, 0);
            }
            *reinterpret_cast<ushort4*>(&Xs[r * 128 + ((c4 * 4) ^ ((r & 7) << 3))]) = pk.v;
        }
        // zero G pad rows R..PAD-1 (width 256 halfs)
        constexpr int GZ = 2 * (PAD - R) * 64;       // ushort4 units
        for (int u = tid; u < GZ; u += 256) {
            const int arr = (u >= (PAD - R) * 64);
            const int rem = arr ? (u - (PAD - R) * 64) : u;
            const int r = R + (rem >> 6), c4 = rem & 63;
            _Float16* Gs = arr ? GT : GH;
            *reinterpret_cast<ushort4*>(&Gs[r * 256 + c4 * 4]) = make_ushort4(0, 0, 0, 0);
        }
    }
    __syncthreads();

    // ---- G_s = x_s @ [WA|WB]^T + [bA|bB]; wave owns 4 col-tiles; fp16 -> LDS ----
#pragma unroll
    for (int side = 0; side < 2; ++side) {
        const _Float16* Xs = side ? XT : XH;
        const float* __restrict__ bA = side ? bT : bH;
        const float* __restrict__ bB = side ? bH : bT;
        _Float16* Gs = side ? GT : GH;

        f32x4 acc[TM][4];
#pragma unroll
        for (int ti = 0; ti < TM; ++ti)
#pragma unroll
            for (int c2 = 0; c2 < 4; ++c2) acc[ti][c2] = (f32x4){0.f, 0.f, 0.f, 0.f};

#pragma unroll
        for (int ks = 0; ks < 4; ++ks) {
            const int k0 = ks * 32 + lq * 8;
            const int kx = k0 ^ ((lm & 7) << 3);     // row = ti*16+lm -> row&7 == lm&7
            f16x8 q[TM];
#pragma unroll
            for (int ti = 0; ti < TM; ++ti)
                q[ti] = *reinterpret_cast<const f16x8*>(&Xs[(ti * 16 + lm) * 128 + kx]);
#pragma unroll
            for (int c2 = 0; c2 < 4; ++c2) {
                const int wfidx = side ? (c2 ^ 2) : c2;
#pragma unroll
                for (int ti = 0; ti < TM; ++ti)
                    acc[ti][c2] = __builtin_amdgcn_mfma_f32_16x16x32_f16(
                        wf[wfidx][ks], q[ti], acc[ti][c2], 0, 0, 0);
            }
        }

        // epilogue: lane holds G[i=ti*16+lm][n=ctl*16+lq*4+r]
#pragma unroll
        for (int c2 = 0; c2 < 4; ++c2) {
            const int ctl = (c2 < 2) ? (tile0 + c2) : (8 + tile0 + (c2 - 2));
            const int nc = ctl * 16 + lq * 4;
            const float* bp = (ctl < 8) ? (bA + nc) : (bB + nc - 128);
            float4 b4 = *reinterpret_cast<const float4*>(bp);
#pragma unroll
            for (int ti = 0; ti < TM; ++ti) {
                int i = ti * 16 + lm;
                if (i < R) {
                    PK4 pk;
                    pk.h[0] = (_Float16)(acc[ti][c2][0] + b4.x);
                    pk.h[1] = (_Float16)(acc[ti][c2][1] + b4.y);
                    pk.h[2] = (_Float16)(acc[ti][c2][2] + b4.z);
                    pk.h[3] = (_Float16)(acc[ti][c2][3] + b4.w);
                    *reinterpret_cast<ushort4*>(&Gs[i * 256 + (nc ^ ((i & 7) << 3))]) = pk.v;
                }
            }
        }
    }
    __syncthreads();

    // ---- alpha = tanh(G_h @ G_t^T); wave w<TM owns i-tile w; no clamps (zero pad) ----
    float cs[3] = {0.f, 0.f, 0.f};
    if (w < TM) {
        f32x4 acc2[TM];
#pragma unroll
        for (int tj = 0; tj < TM; ++tj) acc2[tj] = (f32x4){0.f, 0.f, 0.f, 0.f};

        const int ri = w * 16 + lm;
#pragma unroll
        for (int ksa = 0; ksa < 8; ++ksa) {
            const int k0 = ksa * 32 + lq * 8;
            const int kx = k0 ^ ((lm & 7) << 3);
            f16x8 A = *reinterpret_cast<const f16x8*>(&GH[ri * 256 + kx]);
#pragma unroll
            for (int tj = 0; tj < TM; ++tj) {
                f16x8 B = *reinterpret_cast<const f16x8*>(&GT[(tj * 16 + lm) * 256 + kx]);
                acc2[tj] = __builtin_amdgcn_mfma_f32_16x16x32_f16(A, B, acc2[tj], 0, 0, 0);
            }
        }

        float at[TM][4];
#pragma unroll
        for (int tj = 0; tj < TM; ++tj)
#pragma unroll
            for (int r = 0; r < 4; ++r) at[tj][r] = tanh_fast(acc2[tj][r]);

        // row sums over j -> bh_s[i]
#pragma unroll
        for (int r = 0; r < 4; ++r) {
            float s = 0.f;
#pragma unroll
            for (int tj = 0; tj < TM; ++tj) s += at[tj][r];
            s += __shfl_xor(s, 1, 64);
            s += __shfl_xor(s, 2, 64);
            s += __shfl_xor(s, 4, 64);
            s += __shfl_xor(s, 8, 64);
            if (lm == 0) bh_s[w * 16 + lq * 4 + r] = s;
        }
        // col partial sums over this i-tile
#pragma unroll
        for (int tj = 0; tj < TM; ++tj) {
            float s = 0.f;
#pragma unroll
            for (int r = 0; r < 4; ++r) s += at[tj][r];
            s += __shfl_xor(s, 16, 64);
            s += __shfl_xor(s, 32, 64);
            cs[tj] = s;
        }
    }
#pragma unroll
    for (int tj = 0; tj < 3; ++tj)
        if (lq == 0) colpart[w * 48 + tj * 16 + lm] = (tj < TM) ? cs[tj] : 0.f;
    __syncthreads();

    // ---- softmaxes: wave0 -> p_t (col means), wave1 -> p_h (row means) ----
    if (w == 0) {
        float v = (l < 48) ? (colpart[l] + colpart[48 + l] + colpart[96 + l] + colpart[144 + l]) : 0.f;
        float val = (l < R) ? v * invR : -INFINITY;
        float m = val;
        for (int o = 32; o; o >>= 1) m = fmaxf(m, __shfl_xor(m, o, 64));
        float e = (l < R) ? __expf(val - m) : 0.f;
        float s = e;
        for (int o = 32; o; o >>= 1) s += __shfl_xor(s, o, 64);
        if (l < R) pt_s[l] = e / s;
    } else if (w == 1) {
        float val = (l < R) ? bh_s[l] * invR : -INFINITY;
        float m = val;
        for (int o = 32; o; o >>= 1) m = fmaxf(m, __shfl_xor(m, o, 64));
        float e = (l < R) ? __expf(val - m) : 0.f;
        float s = e;
        for (int o = 32; o; o >>= 1) s += __shfl_xor(s, o, 64);
        if (l < R) ph_s[l] = e / s;
    }
    __syncthreads();

    // ---- outputs from LDS fp16 x copies ----
    if (tid < 128) {
        const int c = tid;
        float a = 0.f;
        for (int j = 0; j < R; ++j)
            a += pt_s[j] * (float)XT[j * 128 + (c ^ ((j & 7) << 3))];
        ost[g * D + c] = a;
    } else {
        const int c = tid - 128;
        float a = 0.f;
        for (int i = 0; i < R; ++i)
            a += ph_s[i] * (float)XH[i * 128 + (c ^ ((i & 7) << 3))];
        osh[g * D + c] = a;
    }
}

__global__ __launch_bounds__(256, 2) void fused_kernel(
    const float* __restrict__ xnh, const float* __restrict__ xnt,
    const float* __restrict__ xlh, const float* __restrict__ xlt,
    const float* __restrict__ Wh, const float* __restrict__ bh,
    const float* __restrict__ Wt, const float* __restrict__ bt,
    const float* __restrict__ Whl, const float* __restrict__ bhl,
    const float* __restrict__ Wtl, const float* __restrict__ btl,
    float* __restrict__ out)
{
    __shared__ __align__(16) _Float16 GH[48 * 256];
    __shared__ __align__(16) _Float16 GT[48 * 256];
    __shared__ __align__(16) _Float16 XH[48 * 128];
    __shared__ __align__(16) _Float16 XT[48 * 128];
    __shared__ float colpart[192], bh_s[48], pt_s[48], ph_s[48];

    int idx = blockIdx.x;
    if (idx < 256)
        body<0>(idx, xnh, xnt, Wh, Wt, bh, bt, out + 0, out + 32768,
                GH, GT, XH, XT, colpart, bh_s, pt_s, ph_s);
    else
        body<1>(idx - 256, xlh, xlt, Whl, Wtl, bhl, btl, out + 65536, out + 98304,
                GH, GT, XH, XT, colpart, bh_s, pt_s, ph_s);
}

extern "C" void kernel_launch(void* const* d_in, const int* in_sizes, int n_in,
                              void* d_out, int out_size, void* d_ws, size_t ws_size,
                              hipStream_t stream) {
    const float* xnh   = (const float*)d_in[0];
    const float* xnt   = (const float*)d_in[1];
    const float* xlh   = (const float*)d_in[2];
    const float* xlt   = (const float*)d_in[3];
    const float* Wh_w  = (const float*)d_in[4];
    const float* Wh_b  = (const float*)d_in[5];
    const float* Wt_w  = (const float*)d_in[6];
    const float* Wt_b  = (const float*)d_in[7];
    const float* Whl_w = (const float*)d_in[8];
    const float* Whl_b = (const float*)d_in[9];
    const float* Wtl_w = (const float*)d_in[10];
    const float* Wtl_b = (const float*)d_in[11];

    float* out = (float*)d_out;

    fused_kernel<<<512, 256, 0, stream>>>(xnh, xnt, xlh, xlt,
                                          Wh_w, Wh_b, Wt_w, Wt_b,
                                          Whl_w, Whl_b, Wtl_w, Wtl_b, out);
}